// Round 1
// baseline (22730.534 us; speedup 1.0000x reference)
//
#include <hip/hip_runtime.h>
#include <hip/hip_bf16.h>

#define DIMS 1024
#define SEQ 512
#define BATCH 128
#define VOCAB 32000
#define GRID 256

typedef __attribute__((ext_vector_type(8))) short short8;
typedef __attribute__((ext_vector_type(4))) float f32x4;

__device__ __forceinline__ ushort f2bf(float x) {
    union { float f; unsigned u; } v; v.f = x;
    unsigned u = v.u;
    return (ushort)((u + 0x7FFFu + ((u >> 16) & 1u)) >> 16);
}

__global__ void conv_emb_kernel(const float* __restrict__ in, ushort* __restrict__ out, int n) {
    int idx = blockIdx.x * blockDim.x + threadIdx.x;
    int stride = gridDim.x * blockDim.x;
    for (int i = idx * 4; i < n; i += stride * 4) {
        float4 v = *(const float4*)(in + i);
        ushort4 o;
        o.x = f2bf(v.x); o.y = f2bf(v.y); o.z = f2bf(v.z); o.w = f2bf(v.w);
        *(ushort4*)(out + i) = o;
    }
}

// Persistent LSTM kernel.
// Grid = 256 blocks = 2 row-groups (64 batch rows) x 128 d-chunks (8 d cols).
// Block keeps its B-slice ([W;U] for its 32 preact cols, K=2048) in LDS for all
// 512 steps, and its c-state slice in registers. Per step: fused GEMM
// preact[64x32] = [xt;h] @ Bslice, activations, h written to global (bf16,
// double-buffered), then one agent-scope atomic barrier.
__launch_bounds__(256, 1)
__global__ void lstm_kernel(const int* __restrict__ feats,
                            const ushort* __restrict__ emb,
                            const float* __restrict__ Wf, const float* __restrict__ Uf, const float* __restrict__ bfp,
                            const float* __restrict__ Wi, const float* __restrict__ Ui, const float* __restrict__ bip,
                            const float* __restrict__ Wo, const float* __restrict__ Uo, const float* __restrict__ bop,
                            const float* __restrict__ Wc, const float* __restrict__ Uc, const float* __restrict__ bcp,
                            ushort* __restrict__ hbuf, float* __restrict__ out, int* __restrict__ bar) {
    // B slice in LDS: 32 cols x 2048 k, bf16, XOR-swizzled to avoid bank conflicts
    __shared__ ushort Bl[32 * 2048];       // 131072 B
    __shared__ float pre[64][33];          // 8448 B preactivation staging

    const int tid = threadIdx.x;
    const int bid = blockIdx.x;
    const int rg = bid >> 7;      // row group: rows rg*64 .. rg*64+63
    const int cb = bid & 127;     // d-chunk: d = cb*8 .. cb*8+7

    // ---- one-time: load B slice (f32 -> bf16) into LDS ----
    // col index cl = gate*8 + dd, gate order {f,i,o,c}; k<1024 -> W, else U.
    for (int idx = tid; idx < 32 * 2048; idx += 256) {
        int cl = idx >> 11;
        int k  = idx & 2047;
        int g  = cl >> 3, dd = cl & 7;
        int d  = cb * 8 + dd;
        const float* Wg = (g == 0) ? Wf : (g == 1) ? Wi : (g == 2) ? Wo : Wc;
        const float* Ug = (g == 0) ? Uf : (g == 1) ? Ui : (g == 2) ? Uo : Uc;
        float v = (k < 1024) ? Wg[k * 1024 + d] : Ug[(k - 1024) * 1024 + d];
        int boff = ((cl << 12) | (k << 1)) ^ ((cl & 7) << 4);
        *(ushort*)((char*)Bl + boff) = f2bf(v);
    }
    __syncthreads();

    const int lane = tid & 63;
    const int w = tid >> 6;            // wave 0..3, owns rows w*16..w*16+15
    const int lx = lane & 15;          // A-frag row / B-frag col within tile
    const int kg = (lane >> 4) * 8;    // k sub-offset within a 32-k step
    const int brow = rg * 64 + w * 16 + lx;   // global batch row for A-frag

    // LDS byte offset bases for the two B n-tiles (n = lx and n = 16+lx).
    // full offset = base ^ (k<<1)   (bits disjoint / XOR-swizzle on bits 4..6)
    const int bofs0 = (lx << 12) ^ ((lx & 7) << 4);
    const int bofs1 = ((16 + lx) << 12) ^ ((lx & 7) << 4);

    // c-state: thread owns states sid = tid*2+{0,1}: row = sid>>3, dd = sid&7
    float cst[2] = {0.f, 0.f};

    for (int t = 0; t < SEQ; t++) {
        const ushort* hprev = hbuf + (t & 1) * (BATCH * DIMS);
        ushort* hnext = hbuf + ((t + 1) & 1) * (BATCH * DIMS);

        int fidx = feats[brow * SEQ + t];
        const ushort* xrow = emb + (size_t)fidx * DIMS;
        const ushort* hrow = hprev + brow * DIMS;

        f32x4 acc0 = {0.f, 0.f, 0.f, 0.f};
        f32x4 acc1 = {0.f, 0.f, 0.f, 0.f};

        // x @ W part: k = 0..1023
        #pragma unroll 8
        for (int ks = 0; ks < 32; ks++) {
            int k = ks * 32 + kg;
            short8 a  = *(const short8*)(xrow + k);
            short8 b0 = *(const short8*)((const char*)Bl + (bofs0 ^ (k << 1)));
            short8 b1 = *(const short8*)((const char*)Bl + (bofs1 ^ (k << 1)));
            acc0 = __builtin_amdgcn_mfma_f32_16x16x32_bf16(a, b0, acc0, 0, 0, 0);
            acc1 = __builtin_amdgcn_mfma_f32_16x16x32_bf16(a, b1, acc1, 0, 0, 0);
        }
        // h @ U part: k = 1024..2047
        #pragma unroll 8
        for (int ks = 32; ks < 64; ks++) {
            int k = ks * 32 + kg;
            short8 a  = *(const short8*)(hrow + (k - 1024));
            short8 b0 = *(const short8*)((const char*)Bl + (bofs0 ^ (k << 1)));
            short8 b1 = *(const short8*)((const char*)Bl + (bofs1 ^ (k << 1)));
            acc0 = __builtin_amdgcn_mfma_f32_16x16x32_bf16(a, b0, acc0, 0, 0, 0);
            acc1 = __builtin_amdgcn_mfma_f32_16x16x32_bf16(a, b1, acc1, 0, 0, 0);
        }

        // C/D layout (m89): col = lane&15, row = (lane>>4)*4 + reg
        int r0 = w * 16 + (lane >> 4) * 4;
        #pragma unroll
        for (int j = 0; j < 4; j++) {
            pre[r0 + j][lx]      = acc0[j];
            pre[r0 + j][16 + lx] = acc1[j];
        }
        __syncthreads();

        // elementwise gates + state update: 512 (row,dd) states, 2 per thread
        #pragma unroll
        for (int s = 0; s < 2; s++) {
            int sid = tid * 2 + s;
            int row = sid >> 3;
            int dd  = sid & 7;
            int d   = cb * 8 + dd;
            float pf = pre[row][dd]      + bfp[d];
            float pi = pre[row][8 + dd]  + bip[d];
            float po = pre[row][16 + dd] + bop[d];
            float pc = pre[row][24 + dd] + bcp[d];
            float f  = 1.f / (1.f + __expf(-pf));
            float ig = 1.f / (1.f + __expf(-pi));
            float o  = 1.f / (1.f + __expf(-po));
            float e2 = __expf(2.f * pc);
            float cc = (e2 - 1.f) / (e2 + 1.f);
            float cn = f * cst[s] + ig * cc;
            cst[s] = cn;
            float e2c = __expf(2.f * cn);
            float th  = (e2c - 1.f) / (e2c + 1.f);
            float h   = o * th;
            int grow = rg * 64 + row;
            hnext[grow * DIMS + d] = f2bf(h);
            if (t == SEQ - 1) {
                out[grow * 2048 + d] = h;
                out[grow * 2048 + 1024 + d] = cn;
            }
        }

        if (t < SEQ - 1) {
            __threadfence();
            __syncthreads();
            if (tid == 0) {
                __hip_atomic_fetch_add(bar, 1, __ATOMIC_ACQ_REL, __HIP_MEMORY_SCOPE_AGENT);
                int target = GRID * (t + 1);
                long guard = 0;
                while (__hip_atomic_load(bar, __ATOMIC_ACQUIRE, __HIP_MEMORY_SCOPE_AGENT) < target) {
                    __builtin_amdgcn_s_sleep(4);
                    if (++guard > 400000000L) break;  // deadlock safety valve
                }
            }
            __syncthreads();
        }
    }
}

extern "C" void kernel_launch(void* const* d_in, const int* in_sizes, int n_in,
                              void* d_out, int out_size, void* d_ws, size_t ws_size,
                              hipStream_t stream) {
    const int*   feats = (const int*)d_in[0];
    const float* emb_f = (const float*)d_in[1];
    const float* Wf = (const float*)d_in[2];
    const float* Uf = (const float*)d_in[3];
    const float* bf_ = (const float*)d_in[4];
    const float* Wi = (const float*)d_in[5];
    const float* Ui = (const float*)d_in[6];
    const float* bi_ = (const float*)d_in[7];
    const float* Wo = (const float*)d_in[8];
    const float* Uo = (const float*)d_in[9];
    const float* bo_ = (const float*)d_in[10];
    const float* Wc = (const float*)d_in[11];
    const float* Uc = (const float*)d_in[12];
    const float* bc_ = (const float*)d_in[13];

    char* ws = (char*)d_ws;
    ushort* emb_bf = (ushort*)ws;                          // 65,536,000 B
    ushort* hbuf   = (ushort*)(ws + 65536000);             // 2 x 128 x 1024 bf16 = 524,288 B
    int*    bar    = (int*)(ws + 65536000 + 524288);       // barrier counter

    hipMemsetAsync(hbuf, 0, 524288 + 64, stream);
    conv_emb_kernel<<<1024, 256, 0, stream>>>(emb_f, emb_bf, VOCAB * DIMS);
    lstm_kernel<<<GRID, 256, 0, stream>>>(feats, emb_bf,
                                          Wf, Uf, bf_, Wi, Ui, bi_,
                                          Wo, Uo, bo_, Wc, Uc, bc_,
                                          hbuf, (float*)d_out, bar);
}